// Round 1
// baseline (909.669 us; speedup 1.0000x reference)
//
#include <hip/hip_runtime.h>

// Problem: CrossModalAttention  B=8, CQ=CKV=E=256, H=W=64 (Nq=4096), HP=WP=32 (Nkv=1024)
// out = concat([C, out_w @ (gP @ softmax(thetaC^T @ phiP / 16)^T)], axis=1)

#define B_   8
#define E_   256
#define NQ_  4096
#define NKV_ 1024

// ---------------- small prep kernels ----------------

__global__ __launch_bounds__(256) void transpose_w_k(const float* __restrict__ W,
                                                     float* __restrict__ WT) {
    int c = blockIdx.x;      // 0..255
    int e = threadIdx.x;     // 0..255
    WT[e * 256 + c] = W[c * 256 + e];
}

__global__ __launch_bounds__(256) void copy_c_k(const float4* __restrict__ C,
                                                float4* __restrict__ out) {
    size_t i = (size_t)blockIdx.x * blockDim.x + threadIdx.x; // over B*256*1024 float4
    size_t b = i >> 18;                // / (256*1024)
    size_t r = i & ((size_t)(1 << 18) - 1);
    out[(b << 19) + r] = C[i];         // out batch stride = 512*1024 float4
}

// ---------------- projection GEMM: Y = W[M,K] * X[b][K,N]  (M=K=256) ----------------
// TRANS_OUT=0: Y[b][M][N];  TRANS_OUT=1: Y[b][N][M]

template <int TRANS_OUT>
__global__ __launch_bounds__(256) void proj_gemm(const float* __restrict__ W,
                                                 const float* __restrict__ X,
                                                 float* __restrict__ Y,
                                                 int N, float scale) {
    const int K = 256, M = 256;
    int tid = threadIdx.x;
    int tx = tid & 15;   // 0..15
    int ty = tid >> 4;   // 0..15
    int b  = blockIdx.z;
    int n0 = blockIdx.x * 64;
    int m0 = blockIdx.y * 64;

    const float* Xb = X + (size_t)b * K * N;
    float* Yb = Y + (size_t)b * (size_t)M * N;

    __shared__ float Ws[16][64];  // [k][m]
    __shared__ float Xs[16][64];  // [k][n]

    float acc[4][4] = {};

    for (int k0 = 0; k0 < K; k0 += 16) {
        // W tile: rows m0..m0+63, cols k0..k0+15 -> Ws[k][m]
        {
            int mm = tid >> 2;            // 0..63
            int kk = (tid & 3) * 4;       // 0,4,8,12
            float4 w4 = *(const float4*)&W[(size_t)(m0 + mm) * K + k0 + kk];
            Ws[kk + 0][mm] = w4.x; Ws[kk + 1][mm] = w4.y;
            Ws[kk + 2][mm] = w4.z; Ws[kk + 3][mm] = w4.w;
        }
        // X tile: rows k0..k0+15, cols n0..n0+63 -> Xs[k][n]
        {
            int kk = tid >> 4;            // 0..15
            int nn = (tid & 15) * 4;      // 0..60
            float4 x4 = *(const float4*)&Xb[(size_t)(k0 + kk) * N + n0 + nn];
            *(float4*)&Xs[kk][nn] = x4;
        }
        __syncthreads();
#pragma unroll
        for (int kk = 0; kk < 16; ++kk) {
            float4 a4 = *(float4*)&Ws[kk][ty * 4];
            float4 x4 = *(float4*)&Xs[kk][tx * 4];
            float a[4] = {a4.x, a4.y, a4.z, a4.w};
            float x[4] = {x4.x, x4.y, x4.z, x4.w};
#pragma unroll
            for (int i = 0; i < 4; ++i)
#pragma unroll
                for (int j = 0; j < 4; ++j) acc[i][j] += a[i] * x[j];
        }
        __syncthreads();
    }

    if constexpr (TRANS_OUT == 0) {
#pragma unroll
        for (int i = 0; i < 4; ++i) {
            int row = m0 + ty * 4 + i;
            float4 v = make_float4(acc[i][0] * scale, acc[i][1] * scale,
                                   acc[i][2] * scale, acc[i][3] * scale);
            *(float4*)&Yb[(size_t)row * N + n0 + tx * 4] = v;
        }
    } else {
        __shared__ float tile[64][65];
#pragma unroll
        for (int i = 0; i < 4; ++i)
#pragma unroll
            for (int j = 0; j < 4; ++j)
                tile[tx * 4 + j][ty * 4 + i] = acc[i][j] * scale;
        __syncthreads();
        int r = tid >> 2;            // 0..63 (n-row within tile)
        int cq = (tid & 3) * 16;     // 16-float chunk of m
#pragma unroll
        for (int q = 0; q < 16; q += 4) {
            float4 v = make_float4(tile[r][cq + q + 0], tile[r][cq + q + 1],
                                   tile[r][cq + q + 2], tile[r][cq + q + 3]);
            *(float4*)&Yb[(size_t)(n0 + r) * M + m0 + cq + q] = v;
        }
    }
}

// ---------------- fused attention: softmax(thT*phi) -> PV -> out_w proj ----------------
// thetaT [B][NQ][E] (pre-scaled 1/16), phi [B][E][NKV], gT [B][NKV][E], owT [E][CQ]
// writes out[b][256+c][n] for 4 consecutive n per block.

__global__ __launch_bounds__(256) void attn_fused(const float* __restrict__ thetaT,
                                                  const float* __restrict__ phi,
                                                  const float* __restrict__ gT,
                                                  const float* __restrict__ owT,
                                                  float* __restrict__ out) {
    int b = blockIdx.y;
    int nbase = blockIdx.x * 4;
    int t = threadIdx.x;
    int lane = t & 63, wid = t >> 6;

    const float* thp = thetaT + ((size_t)b * NQ_ + nbase) * E_;
    const float* php = phi + (size_t)b * E_ * NKV_;
    const float* gp  = gT + (size_t)b * NKV_ * E_;

    __shared__ float thT[256][4];    // [e][j]
    __shared__ float sT[1024][4];    // [m][j]
    __shared__ float ovT[256][4];    // [e][j]
    __shared__ float red[2][4][4];   // [phase][j][wave]

    // load 4 theta rows (1024 floats), store transposed
    {
        float4 v = *(const float4*)&thp[t * 4];
        int row = t >> 6;            // j
        int col = (t & 63) * 4;      // e
        thT[col + 0][row] = v.x; thT[col + 1][row] = v.y;
        thT[col + 2][row] = v.z; thT[col + 3][row] = v.w;
    }
    __syncthreads();

    // ---- S = thT . phi  (each thread: 4 consecutive m for 4 q-rows) ----
    int m4 = t * 4;
    float acc[4][4] = {};
#pragma unroll 4
    for (int e = 0; e < 256; ++e) {
        float4 tv  = *(float4*)&thT[e][0];
        float4 ph4 = *(const float4*)&php[(size_t)e * NKV_ + m4];
        acc[0][0] += tv.x * ph4.x; acc[0][1] += tv.x * ph4.y;
        acc[0][2] += tv.x * ph4.z; acc[0][3] += tv.x * ph4.w;
        acc[1][0] += tv.y * ph4.x; acc[1][1] += tv.y * ph4.y;
        acc[1][2] += tv.y * ph4.z; acc[1][3] += tv.y * ph4.w;
        acc[2][0] += tv.z * ph4.x; acc[2][1] += tv.z * ph4.y;
        acc[2][2] += tv.z * ph4.z; acc[2][3] += tv.z * ph4.w;
        acc[3][0] += tv.w * ph4.x; acc[3][1] += tv.w * ph4.y;
        acc[3][2] += tv.w * ph4.z; acc[3][3] += tv.w * ph4.w;
    }

    // ---- softmax over m (1024) per q-row ----
    float rmax[4], rinv[4];
#pragma unroll
    for (int j = 0; j < 4; ++j) {
        float pm = fmaxf(fmaxf(acc[j][0], acc[j][1]), fmaxf(acc[j][2], acc[j][3]));
#pragma unroll
        for (int off = 32; off; off >>= 1) pm = fmaxf(pm, __shfl_xor(pm, off));
        if (lane == 0) red[0][j][wid] = pm;
    }
    __syncthreads();
#pragma unroll
    for (int j = 0; j < 4; ++j)
        rmax[j] = fmaxf(fmaxf(red[0][j][0], red[0][j][1]),
                        fmaxf(red[0][j][2], red[0][j][3]));

    float p[4][4];
#pragma unroll
    for (int j = 0; j < 4; ++j) {
        float s = 0.f;
#pragma unroll
        for (int k = 0; k < 4; ++k) {
            p[j][k] = __expf(acc[j][k] - rmax[j]);
            s += p[j][k];
        }
#pragma unroll
        for (int off = 32; off; off >>= 1) s += __shfl_xor(s, off);
        if (lane == 0) red[1][j][wid] = s;
    }
    __syncthreads();
#pragma unroll
    for (int j = 0; j < 4; ++j)
        rinv[j] = 1.f / (red[1][j][0] + red[1][j][1] + red[1][j][2] + red[1][j][3]);

#pragma unroll
    for (int k = 0; k < 4; ++k) {
        float4 sv = make_float4(p[0][k] * rinv[0], p[1][k] * rinv[1],
                                p[2][k] * rinv[2], p[3][k] * rinv[3]);
        *(float4*)&sT[m4 + k][0] = sv;
    }
    __syncthreads();

    // ---- PV: ovT[e][j] = sum_m gT[m][e] * sT[m][j], lane-per-e ----
    float accO[4] = {0.f, 0.f, 0.f, 0.f};
    {
        int e = t; // 0..255, coalesced within wave
#pragma unroll 4
        for (int m = 0; m < 1024; ++m) {
            float g = gp[(size_t)m * 256 + e];
            float4 sv = *(float4*)&sT[m][0];
            accO[0] += g * sv.x; accO[1] += g * sv.y;
            accO[2] += g * sv.z; accO[3] += g * sv.w;
        }
        *(float4*)&ovT[e][0] = make_float4(accO[0], accO[1], accO[2], accO[3]);
    }
    __syncthreads();

    // ---- final projection: out2[c][n] = sum_e owT[e][c] * ovT[e][j] ----
    float accF[4] = {0.f, 0.f, 0.f, 0.f};
#pragma unroll 4
    for (int e2 = 0; e2 < 256; ++e2) {
        float w = owT[(size_t)e2 * 256 + t];
        float4 o4 = *(float4*)&ovT[e2][0];
        accF[0] += w * o4.x; accF[1] += w * o4.y;
        accF[2] += w * o4.z; accF[3] += w * o4.w;
    }
    float* op = out + (size_t)b * 512 * 4096 + (size_t)(256 + t) * 4096 + nbase;
    *(float4*)op = make_float4(accF[0], accF[1], accF[2], accF[3]);
}

// ---------------- launch ----------------

extern "C" void kernel_launch(void* const* d_in, const int* in_sizes, int n_in,
                              void* d_out, int out_size, void* d_ws, size_t ws_size,
                              hipStream_t stream) {
    const float* C       = (const float*)d_in[0];
    const float* P       = (const float*)d_in[1];
    const float* theta_w = (const float*)d_in[2];
    const float* phi_w   = (const float*)d_in[3];
    const float* g_w     = (const float*)d_in[4];
    const float* out_w   = (const float*)d_in[5];
    float* out = (float*)d_out;

    float* ws = (float*)d_ws;
    float* thetaT = ws;                                   // 8*4096*256
    float* phiP   = thetaT + (size_t)B_ * NQ_ * E_;       // 8*256*1024
    float* gTP    = phiP + (size_t)B_ * E_ * NKV_;        // 8*1024*256
    float* owT    = gTP + (size_t)B_ * NKV_ * E_;         // 256*256

    transpose_w_k<<<dim3(256), dim3(256), 0, stream>>>(out_w, owT);
    copy_c_k<<<dim3(8192), dim3(256), 0, stream>>>((const float4*)C, (float4*)out);

    // thetaC^T [B][4096][256], scaled by 1/sqrt(E)=1/16
    proj_gemm<1><<<dim3(64, 4, 8), dim3(256), 0, stream>>>(theta_w, C, thetaT, NQ_, 1.f / 16.f);
    // phiP [B][256][1024]
    proj_gemm<0><<<dim3(16, 4, 8), dim3(256), 0, stream>>>(phi_w, P, phiP, NKV_, 1.f);
    // gP^T [B][1024][256]
    proj_gemm<1><<<dim3(16, 4, 8), dim3(256), 0, stream>>>(g_w, P, gTP, NKV_, 1.f);

    attn_fused<<<dim3(NQ_ / 4, B_), dim3(256), 0, stream>>>(thetaT, phiP, gTP, owT, out);
}

// Round 2
// 251.478 us; speedup vs baseline: 3.6173x; 3.6173x over previous
//
#include <hip/hip_runtime.h>

// CrossModalAttention  B=8, CQ=CKV=E=256, Nq=4096, Nkv=1024
// out = concat([C, out_w @ (gP @ softmax(thetaC^T @ phiP / 16)^T)], axis=1)

#define B_   8
#define E_   256
#define NQ_  4096
#define NKV_ 1024

typedef __attribute__((ext_vector_type(8))) short short8;   // 8 bf16 (raw bits)
typedef __attribute__((ext_vector_type(4))) float f32x4;

__device__ __forceinline__ unsigned short f2bf(float f) {
    unsigned int u = __float_as_uint(f);
    u += 0x7FFFu + ((u >> 16) & 1u);            // RNE
    return (unsigned short)(u >> 16);
}

// ---------------- small prep kernels ----------------

__global__ __launch_bounds__(256) void cvt_ow(const float* __restrict__ W,
                                              unsigned short* __restrict__ O) {
    int i = blockIdx.x * 256 + threadIdx.x;     // over 16384 float4
    float4 v = ((const float4*)W)[i];
    ushort4 o; o.x = f2bf(v.x); o.y = f2bf(v.y); o.z = f2bf(v.z); o.w = f2bf(v.w);
    ((ushort4*)O)[i] = o;
}

__global__ __launch_bounds__(256) void copy_c_k(const float4* __restrict__ C,
                                                float4* __restrict__ out) {
    size_t i = (size_t)blockIdx.x * blockDim.x + threadIdx.x; // over B*256*1024 float4
    size_t b = i >> 18;
    size_t r = i & ((size_t)(1 << 18) - 1);
    out[(b << 19) + r] = C[i];
}

// ---------------- projection GEMM: Y = W[256,256] * X[b][256,N], bf16 out ----------------
// TRANS_OUT=0: Y[b][M][N];  TRANS_OUT=1: Y[b][N][M]

template <int TRANS_OUT>
__global__ __launch_bounds__(256) void proj_gemm_bf(const float* __restrict__ W,
                                                    const float* __restrict__ X,
                                                    unsigned short* __restrict__ Y,
                                                    int N, float scale) {
    const int K = 256, M = 256;
    int tid = threadIdx.x;
    int tx = tid & 15;
    int ty = tid >> 4;
    int b  = blockIdx.z;
    int n0 = blockIdx.x * 64;
    int m0 = blockIdx.y * 64;

    const float* Xb = X + (size_t)b * K * N;
    unsigned short* Yb = Y + (size_t)b * (size_t)M * N;

    __shared__ float Ws[16][64];
    __shared__ float Xs[16][64];

    float acc[4][4] = {};

    for (int k0 = 0; k0 < K; k0 += 16) {
        {
            int mm = tid >> 2;
            int kk = (tid & 3) * 4;
            float4 w4 = *(const float4*)&W[(size_t)(m0 + mm) * K + k0 + kk];
            Ws[kk + 0][mm] = w4.x; Ws[kk + 1][mm] = w4.y;
            Ws[kk + 2][mm] = w4.z; Ws[kk + 3][mm] = w4.w;
        }
        {
            int kk = tid >> 4;
            int nn = (tid & 15) * 4;
            float4 x4 = *(const float4*)&Xb[(size_t)(k0 + kk) * N + n0 + nn];
            *(float4*)&Xs[kk][nn] = x4;
        }
        __syncthreads();
#pragma unroll
        for (int kk = 0; kk < 16; ++kk) {
            float4 a4 = *(float4*)&Ws[kk][ty * 4];
            float4 x4 = *(float4*)&Xs[kk][tx * 4];
            float a[4] = {a4.x, a4.y, a4.z, a4.w};
            float x[4] = {x4.x, x4.y, x4.z, x4.w};
#pragma unroll
            for (int i = 0; i < 4; ++i)
#pragma unroll
                for (int j = 0; j < 4; ++j) acc[i][j] += a[i] * x[j];
        }
        __syncthreads();
    }

    if constexpr (TRANS_OUT == 0) {
#pragma unroll
        for (int i = 0; i < 4; ++i) {
            int row = m0 + ty * 4 + i;
            ushort4 v;
            v.x = f2bf(acc[i][0] * scale); v.y = f2bf(acc[i][1] * scale);
            v.z = f2bf(acc[i][2] * scale); v.w = f2bf(acc[i][3] * scale);
            *(ushort4*)&Yb[(size_t)row * N + n0 + tx * 4] = v;
        }
    } else {
        __shared__ float tile[64][65];
#pragma unroll
        for (int i = 0; i < 4; ++i)
#pragma unroll
            for (int j = 0; j < 4; ++j)
                tile[tx * 4 + j][ty * 4 + i] = acc[i][j] * scale;
        __syncthreads();
        int r = tid >> 2;
        int cq = (tid & 3) * 16;
#pragma unroll
        for (int q = 0; q < 16; q += 4) {
            ushort4 v;
            v.x = f2bf(tile[r][cq + q + 0]); v.y = f2bf(tile[r][cq + q + 1]);
            v.z = f2bf(tile[r][cq + q + 2]); v.w = f2bf(tile[r][cq + q + 3]);
            *(ushort4*)&Yb[(size_t)(n0 + r) * M + m0 + cq + q] = v;
        }
    }
}

// ---------------- fused MFMA attention ----------------
// thetaT [B][4096][256] bf16 (pre-scaled by log2e/16), phiT [B][1024][256] bf16,
// gP [B][256][1024] bf16, owB [256][256] bf16. Writes out[b][256+c][q].
// Block: 64 q-rows, 4 waves (16 q-rows each). KV tiles of 64, online softmax (exp2 domain).

__global__ __launch_bounds__(256) void attn_mfma(const unsigned short* __restrict__ thetaT,
                                                 const unsigned short* __restrict__ phiT,
                                                 const unsigned short* __restrict__ gP,
                                                 const unsigned short* __restrict__ owB,
                                                 float* __restrict__ out) {
    const int b   = blockIdx.y;
    const int q0  = blockIdx.x * 64;
    const int tid = threadIdx.x;
    const int lane = tid & 63;
    const int wid  = tid >> 6;
    const int l15  = lane & 15;
    const int lgr  = lane >> 4;   // 0..3

    __shared__ __align__(16) unsigned short Ks[64 * 256];   // 32 KB [m][e], XOR swz (512B rows)
    __shared__ __align__(16) unsigned short Vs[256 * 64];   // 32 KB [e][m], XOR swz (128B rows)
    __shared__ __align__(16) unsigned short Ps[4][16 * 64]; // 2 KB/wave [q][m], XOR swz

    // ---- Q fragments in registers (16 q-rows per wave, K=256 in 8 steps) ----
    short8 qf[8];
    {
        const unsigned short* thp =
            thetaT + ((size_t)b * NQ_ + q0 + wid * 16 + l15) * E_ + lgr * 8;
#pragma unroll
        for (int ks = 0; ks < 8; ++ks)
            qf[ks] = *(const short8*)(thp + ks * 32);
    }

    f32x4 o[16];
#pragma unroll
    for (int nf = 0; nf < 16; ++nf) o[nf] = (f32x4){0.f, 0.f, 0.f, 0.f};
    float rm[4] = {-1e30f, -1e30f, -1e30f, -1e30f};
    float rl[4] = {0.f, 0.f, 0.f, 0.f};

    char* PwC = (char*)&Ps[wid][0];

    for (int mt = 0; mt < 16; ++mt) {
        const int m0 = mt * 64;
        // ---- stage K tile [64][256] (contiguous 32 KB) ----
        {
            const unsigned short* gk = phiT + ((size_t)b * NKV_ + m0) * E_;
            short8 kt[8];
#pragma unroll
            for (int i = 0; i < 8; ++i)
                kt[i] = *(const short8*)(gk + (i * 256 + tid) * 8);
#pragma unroll
            for (int i = 0; i < 8; ++i) {
                unsigned off = (unsigned)(i * 256 + tid) * 16u;
                off ^= ((off >> 9) & 7u) << 4;
                *(short8*)((char*)Ks + off) = kt[i];
            }
        }
        // ---- stage V tile [256 e][64 m] (rows strided in global) ----
        {
            const unsigned short* gv = gP + (size_t)b * E_ * NKV_ + m0;
            short8 vt[8];
#pragma unroll
            for (int i = 0; i < 8; ++i) {
                int e = i * 32 + (tid >> 3);
                vt[i] = *(const short8*)(gv + (size_t)e * NKV_ + (tid & 7) * 8);
            }
#pragma unroll
            for (int i = 0; i < 8; ++i) {
                int e = i * 32 + (tid >> 3);
                unsigned off = ((unsigned)(e * 128 + (tid & 7) * 16)) ^ (((unsigned)e & 7u) << 4);
                *(short8*)((char*)Vs + off) = vt[i];
            }
        }
        __syncthreads();

        // ---- S = Q K^T : 4 m-frags x 8 k-steps ----
        f32x4 s[4];
#pragma unroll
        for (int nf = 0; nf < 4; ++nf) s[nf] = (f32x4){0.f, 0.f, 0.f, 0.f};
#pragma unroll
        for (int ks = 0; ks < 8; ++ks) {
#pragma unroll
            for (int nf = 0; nf < 4; ++nf) {
                int m = nf * 16 + l15;
                int off = (m * 512 + ks * 64 + lgr * 16) ^ ((m & 7) << 4);
                short8 kf = *(const short8*)((const char*)Ks + off);
                s[nf] = __builtin_amdgcn_mfma_f32_16x16x32_bf16(qf[ks], kf, s[nf], 0, 0, 0);
            }
        }

        // ---- online softmax (exp2 domain; row q = lgr*4+r; cols across lane&15 + frags) ----
        float tmax[4];
#pragma unroll
        for (int r = 0; r < 4; ++r) {
            float v = fmaxf(fmaxf(s[0][r], s[1][r]), fmaxf(s[2][r], s[3][r]));
            v = fmaxf(v, __shfl_xor(v, 1));
            v = fmaxf(v, __shfl_xor(v, 2));
            v = fmaxf(v, __shfl_xor(v, 4));
            v = fmaxf(v, __shfl_xor(v, 8));
            tmax[r] = v;
        }
#pragma unroll
        for (int r = 0; r < 4; ++r) {
            if (!__all(tmax[r] - rm[r] <= 8.f)) {   // T13 defer-max
                float nm = fmaxf(rm[r], tmax[r]);
                float sc = __builtin_amdgcn_exp2f(rm[r] - nm);
                rl[r] *= sc;
#pragma unroll
                for (int nf = 0; nf < 16; ++nf) o[nf][r] *= sc;
                rm[r] = nm;
            }
        }
        // ---- P = exp2(S - rm), row-sum, write bf16 P tile to LDS ----
#pragma unroll
        for (int r = 0; r < 4; ++r) {
            int qloc = lgr * 4 + r;
            float ps = 0.f;
#pragma unroll
            for (int nf = 0; nf < 4; ++nf) {
                float p = __builtin_amdgcn_exp2f(s[nf][r] - rm[r]);
                ps += p;
                int off = (qloc * 128 + (nf * 16 + l15) * 2) ^ ((qloc & 7) << 4);
                *(unsigned short*)(PwC + off) = f2bf(p);
            }
            ps += __shfl_xor(ps, 1);
            ps += __shfl_xor(ps, 2);
            ps += __shfl_xor(ps, 4);
            ps += __shfl_xor(ps, 8);
            rl[r] += ps;
        }

        // ---- O += P V : A from P-LDS, B from V-LDS ----
#pragma unroll
        for (int ks2 = 0; ks2 < 2; ++ks2) {
            int aoff = (l15 * 128 + ks2 * 64 + lgr * 16) ^ ((l15 & 7) << 4);
            short8 pf = *(const short8*)((const char*)PwC + aoff);
#pragma unroll
            for (int nf = 0; nf < 16; ++nf) {
                int e = nf * 16 + l15;
                int boff = (e * 128 + ks2 * 64 + lgr * 16) ^ ((e & 7) << 4);
                short8 vf = *(const short8*)((const char*)Vs + boff);
                o[nf] = __builtin_amdgcn_mfma_f32_16x16x32_bf16(pf, vf, o[nf], 0, 0, 0);
            }
        }
        __syncthreads();
    }

    // ---- normalize, O -> LDS bf16 (reuse Ks), fuse out_w projection ----
    float rinv[4];
#pragma unroll
    for (int r = 0; r < 4; ++r) rinv[r] = 1.f / rl[r];

    char* OlC = (char*)(Ks + wid * 4096);   // [16 q][256 e] bf16 per wave, swz 512B rows
#pragma unroll
    for (int nf = 0; nf < 16; ++nf) {
#pragma unroll
        for (int r = 0; r < 4; ++r) {
            int qloc = lgr * 4 + r;
            int e = nf * 16 + l15;
            int off = (qloc * 512 + e * 2) ^ ((qloc & 7) << 4);
            *(unsigned short*)(OlC + off) = f2bf(o[nf][r] * rinv[r]);
        }
    }
    // wave-local write->read; no barrier needed

    f32x4 f[16];
#pragma unroll
    for (int mf = 0; mf < 16; ++mf) f[mf] = (f32x4){0.f, 0.f, 0.f, 0.f};
#pragma unroll
    for (int ks = 0; ks < 8; ++ks) {
        int boff = (l15 * 512 + ks * 64 + lgr * 16) ^ ((l15 & 7) << 4);
        short8 of = *(const short8*)((const char*)OlC + boff);
        const unsigned short* wrow = owB + ks * 32 + lgr * 8;
#pragma unroll
        for (int mf = 0; mf < 16; ++mf) {
            short8 wf = *(const short8*)(wrow + (size_t)(mf * 16 + l15) * 256);
            f[mf] = __builtin_amdgcn_mfma_f32_16x16x32_bf16(wf, of, f[mf], 0, 0, 0);
        }
    }

    float* op = out + (size_t)b * 512 * 4096 + (size_t)256 * 4096 + q0 + wid * 16 + l15;
#pragma unroll
    for (int mf = 0; mf < 16; ++mf) {
#pragma unroll
        for (int r = 0; r < 4; ++r) {
            int c = mf * 16 + lgr * 4 + r;
            op[(size_t)c * 4096] = f[mf][r];
        }
    }
}

// ---------------- launch ----------------

extern "C" void kernel_launch(void* const* d_in, const int* in_sizes, int n_in,
                              void* d_out, int out_size, void* d_ws, size_t ws_size,
                              hipStream_t stream) {
    const float* C       = (const float*)d_in[0];
    const float* P       = (const float*)d_in[1];
    const float* theta_w = (const float*)d_in[2];
    const float* phi_w   = (const float*)d_in[3];
    const float* g_w     = (const float*)d_in[4];
    const float* out_w   = (const float*)d_in[5];
    float* out = (float*)d_out;

    unsigned short* ws = (unsigned short*)d_ws;
    unsigned short* thetaT = ws;                                  // 8*4096*256
    unsigned short* phiT   = thetaT + (size_t)B_ * NQ_ * E_;      // 8*1024*256
    unsigned short* gPb    = phiT + (size_t)B_ * NKV_ * E_;       // 8*256*1024
    unsigned short* owB    = gPb + (size_t)B_ * E_ * NKV_;        // 256*256

    const float THSC = 1.4426950408889634f / 16.0f;  // log2(e)/sqrt(E)

    cvt_ow<<<dim3(64), dim3(256), 0, stream>>>(out_w, owB);
    copy_c_k<<<dim3(8192), dim3(256), 0, stream>>>((const float4*)C, (float4*)out);

    // thetaT [B][4096][256] bf16, scale folded
    proj_gemm_bf<1><<<dim3(64, 4, 8), dim3(256), 0, stream>>>(theta_w, C, thetaT, NQ_, THSC);
    // phiT [B][1024][256] bf16
    proj_gemm_bf<1><<<dim3(16, 4, 8), dim3(256), 0, stream>>>(phi_w, P, phiT, NKV_, 1.f);
    // gP [B][256][1024] bf16
    proj_gemm_bf<0><<<dim3(16, 4, 8), dim3(256), 0, stream>>>(g_w, P, gPb, NKV_, 1.f);

    attn_mfma<<<dim3(NQ_ / 64, B_), dim3(256), 0, stream>>>(thetaT, phiT, gPb, owB, out);
}

// Round 3
// 245.452 us; speedup vs baseline: 3.7061x; 1.0246x over previous
//
#include <hip/hip_runtime.h>

// CrossModalAttention  B=8, CQ=CKV=E=256, Nq=4096, Nkv=1024
// out = concat([C, (out_w@g_w@P) @ softmax(thetaC^T @ phiP / 16)^T], axis=1)

#define B_   8
#define E_   256
#define NQ_  4096
#define NKV_ 1024

typedef __attribute__((ext_vector_type(8))) short short8;   // 8 bf16 raw
typedef __attribute__((ext_vector_type(16))) float f32x16;
typedef unsigned short ushort_t;

__device__ __forceinline__ unsigned short f2bf(float f) {
    unsigned int u = __float_as_uint(f);
    u += 0x7FFFu + ((u >> 16) & 1u);            // RNE
    return (unsigned short)(u >> 16);
}

__device__ __forceinline__ f32x16 zero16() {
    f32x16 z;
#pragma unroll
    for (int i = 0; i < 16; ++i) z[i] = 0.f;
    return z;
}

__device__ __forceinline__ void gload16(const ushort_t* g, ushort_t* l) {
    __builtin_amdgcn_global_load_lds(
        (const __attribute__((address_space(1))) unsigned int*)g,
        (__attribute__((address_space(3))) unsigned int*)l, 16, 0, 0);
}

// ---------------- small prep kernels ----------------

__global__ __launch_bounds__(256) void copy_c_k(const float4* __restrict__ C,
                                                float4* __restrict__ out) {
    size_t i = (size_t)blockIdx.x * blockDim.x + threadIdx.x; // B*256*1024 float4
    size_t b = i >> 18;
    size_t r = i & ((size_t)(1 << 18) - 1);
    out[(b << 19) + r] = C[i];
}

// W2[c][k] = sum_e out_w[c][e] * g_w[e][k]   (256x256x256 fp32)
__global__ __launch_bounds__(256) void w2_gemm(const float* __restrict__ ow,
                                               const float* __restrict__ gw,
                                               float* __restrict__ W2) {
    int c0 = blockIdx.x * 8;
    int t = threadIdx.x;
    float acc[8] = {};
    for (int e = 0; e < 256; ++e) {
        float g = gw[e * 256 + t];
#pragma unroll
        for (int i = 0; i < 8; ++i) acc[i] += ow[(c0 + i) * 256 + e] * g;
    }
#pragma unroll
    for (int i = 0; i < 8; ++i) W2[(c0 + i) * 256 + t] = acc[i];
}

// ---------------- projection GEMM: Y = W[256,256] * X[b][256,N] -> bf16 ----------------
// MODE 0: thetaT [b][q][e]            (plain transposed)
// MODE 1: phiTx  K-chunk layout: flat = b*262144 + (((m>>6)*32 + (e>>3))*64 + (m&63))*8 + (e&7)
// MODE 2: gVx    V-chunk layout: flat = b*262144 + (((m>>6)*8 + ((m>>3)&7))*256 + e)*8 + (m&7)

template <int MODE>
__global__ __launch_bounds__(256) void proj_gemm_bf(const float* __restrict__ W,
                                                    const float* __restrict__ X,
                                                    ushort_t* __restrict__ Y,
                                                    int N, float scale) {
    const int K = 256;
    int tid = threadIdx.x;
    int tx = tid & 15;
    int ty = tid >> 4;
    int b  = blockIdx.z;
    int n0 = blockIdx.x * 64;
    int m0 = blockIdx.y * 64;

    const float* Xb = X + (size_t)b * K * N;

    __shared__ float Ws[16][64];
    __shared__ float Xs[16][64];

    float acc[4][4] = {};

    for (int k0 = 0; k0 < K; k0 += 16) {
        {
            int mm = tid >> 2;
            int kk = (tid & 3) * 4;
            float4 w4 = *(const float4*)&W[(size_t)(m0 + mm) * K + k0 + kk];
            Ws[kk + 0][mm] = w4.x; Ws[kk + 1][mm] = w4.y;
            Ws[kk + 2][mm] = w4.z; Ws[kk + 3][mm] = w4.w;
        }
        {
            int kk = tid >> 4;
            int nn = (tid & 15) * 4;
            float4 x4 = *(const float4*)&Xb[(size_t)(k0 + kk) * N + n0 + nn];
            *(float4*)&Xs[kk][nn] = x4;
        }
        __syncthreads();
#pragma unroll
        for (int kk = 0; kk < 16; ++kk) {
            float4 a4 = *(float4*)&Ws[kk][ty * 4];
            float4 x4 = *(float4*)&Xs[kk][tx * 4];
            float a[4] = {a4.x, a4.y, a4.z, a4.w};
            float x[4] = {x4.x, x4.y, x4.z, x4.w};
#pragma unroll
            for (int i = 0; i < 4; ++i)
#pragma unroll
                for (int j = 0; j < 4; ++j) acc[i][j] += a[i] * x[j];
        }
        __syncthreads();
    }

    if constexpr (MODE == 2) {
        // rows = e (M-dim), cols = m (N-dim); 4 consecutive m stay in one 8-chunk
#pragma unroll
        for (int i = 0; i < 4; ++i) {
            int e = m0 + ty * 4 + i;
            int m = n0 + tx * 4;
            ushort4 v;
            v.x = f2bf(acc[i][0] * scale); v.y = f2bf(acc[i][1] * scale);
            v.z = f2bf(acc[i][2] * scale); v.w = f2bf(acc[i][3] * scale);
            size_t base = (size_t)b * 262144 +
                          ((size_t)((m >> 6) * 8 + ((m >> 3) & 7)) * 256 + e) * 8 + (m & 7);
            *(ushort4*)&Y[base] = v;
        }
    } else {
        __shared__ float tile[64][65];
#pragma unroll
        for (int i = 0; i < 4; ++i)
#pragma unroll
            for (int j = 0; j < 4; ++j)
                tile[tx * 4 + j][ty * 4 + i] = acc[i][j] * scale;
        __syncthreads();
        int r = tid >> 2;            // 0..63: n-row within tile
        int cq = (tid & 3) * 16;     // e-chunk base
        int n = n0 + r;
#pragma unroll
        for (int q = 0; q < 16; q += 4) {
            int e = m0 + cq + q;
            ushort4 v;
            v.x = f2bf(tile[r][cq + q + 0]); v.y = f2bf(tile[r][cq + q + 1]);
            v.z = f2bf(tile[r][cq + q + 2]); v.w = f2bf(tile[r][cq + q + 3]);
            size_t base;
            if constexpr (MODE == 0)
                base = (size_t)b * 1048576 + (size_t)n * 256 + e;
            else
                base = (size_t)b * 262144 +
                       ((size_t)((n >> 6) * 32 + (e >> 3)) * 64 + (n & 63)) * 8 + (e & 7);
            *(ushort4*)&Y[base] = v;
        }
    }
}

// ---------------- fused MFMA attention (32x32x16, dbuf global_load_lds) ----------------
// thetaT [b][4096][256] bf16 (log2e/16 folded), phiTx/gVx chunk layouts (16384 ushort/tile).
// Block: 4 waves x 32 q-rows = 128 q. 16 KV tiles of 64. Writes out[b][256+e][q] fp32.

__global__ __launch_bounds__(256, 1) void attn2(const ushort_t* __restrict__ thetaT,
                                                const ushort_t* __restrict__ phiTx,
                                                const ushort_t* __restrict__ gVx,
                                                float* __restrict__ out) {
    const int b   = blockIdx.x & 7;     // batch == XCD (blockIdx % 8)
    const int qt  = blockIdx.x >> 3;    // 0..31
    const int tid = threadIdx.x;
    const int lane = tid & 63;
    const int wid  = tid >> 6;
    const int l31  = lane & 31;
    const int lh   = lane >> 5;         // 0/1

    __shared__ __align__(16) ushort_t Kbuf[2][16384];   // 32 KB each, chunk = ec*64 + m
    __shared__ __align__(16) ushort_t Vbuf[2][16384];   // 32 KB each, chunk = mc*256 + e
    __shared__ __align__(16) ushort_t Pbuf[4][2048];    // 4 KB/wave, chunk = mc*32 + q

    const ushort_t* Kg = phiTx + (size_t)b * 262144;
    const ushort_t* Vg = gVx   + (size_t)b * 262144;

    auto stage = [&](int mt, int bufi) {
        const ushort_t* kg = Kg + (size_t)mt * 16384 + (size_t)(wid * 512 + lane) * 8;
        const ushort_t* vg = Vg + (size_t)mt * 16384 + (size_t)(wid * 512 + lane) * 8;
        ushort_t* kl = &Kbuf[bufi][wid * 4096];
        ushort_t* vl = &Vbuf[bufi][wid * 4096];
#pragma unroll
        for (int i = 0; i < 8; ++i) {
            gload16(kg + i * 512, kl + i * 512);
            gload16(vg + i * 512, vl + i * 512);
        }
    };

    stage(0, 0);

    // Q fragments: 32 q-rows/wave, 16 k-steps
    short8 qf[16];
    {
        const ushort_t* qp = thetaT + ((size_t)b * NQ_ + qt * 128 + wid * 32 + l31) * 256 + lh * 8;
#pragma unroll
        for (int ks = 0; ks < 16; ++ks) qf[ks] = *(const short8*)(qp + ks * 16);
    }

    f32x16 o[8];
#pragma unroll
    for (int ef = 0; ef < 8; ++ef) o[ef] = zero16();
    float rm[16], rl[16];
#pragma unroll
    for (int r = 0; r < 16; ++r) { rm[r] = -1e30f; rl[r] = 0.f; }

    ushort_t* Pw = &Pbuf[wid][0];
    int cur = 0;

    __syncthreads();

    for (int mt = 0; mt < 16; ++mt) {
        if (mt < 15) stage(mt + 1, cur ^ 1);

        const ushort_t* Kc = &Kbuf[cur][0];
        const ushort_t* Vc = &Vbuf[cur][0];

        // ---- S = Q K^T ----
        f32x16 s0 = zero16(), s1 = zero16();
#pragma unroll
        for (int ks = 0; ks < 16; ++ks) {
            int ec = ks * 2 + lh;
            short8 k0 = *(const short8*)(Kc + (ec * 64 + l31) * 8);
            short8 k1 = *(const short8*)(Kc + (ec * 64 + 32 + l31) * 8);
            s0 = __builtin_amdgcn_mfma_f32_32x32x16_bf16(qf[ks], k0, s0, 0, 0, 0);
            s1 = __builtin_amdgcn_mfma_f32_32x32x16_bf16(qf[ks], k1, s1, 0, 0, 0);
        }

        // ---- online softmax (exp2 domain); D row r -> q_local=(r&3)+8*(r>>2)+4*lh ----
        float tmax[16];
#pragma unroll
        for (int r = 0; r < 16; ++r) {
            float v = fmaxf(s0[r], s1[r]);
            v = fmaxf(v, __shfl_xor(v, 1));
            v = fmaxf(v, __shfl_xor(v, 2));
            v = fmaxf(v, __shfl_xor(v, 4));
            v = fmaxf(v, __shfl_xor(v, 8));
            v = fmaxf(v, __shfl_xor(v, 16));
            tmax[r] = v;
        }
        float dmax = tmax[0] - rm[0];
#pragma unroll
        for (int r = 1; r < 16; ++r) dmax = fmaxf(dmax, tmax[r] - rm[r]);
        if (!__all(dmax <= 8.f)) {                       // T13 defer-max
#pragma unroll
            for (int r = 0; r < 16; ++r) {
                float nm = fmaxf(rm[r], tmax[r]);
                float sc = __builtin_amdgcn_exp2f(rm[r] - nm);
                rl[r] *= sc;
#pragma unroll
                for (int ef = 0; ef < 8; ++ef) o[ef][r] *= sc;
                rm[r] = nm;
            }
        }
        // P = exp2(S - rm), row-sum, bf16 P tile (chunk = mc*32 + q)
#pragma unroll
        for (int r = 0; r < 16; ++r) {
            int q_l = (r & 3) + 8 * (r >> 2) + 4 * lh;
            float p0 = __builtin_amdgcn_exp2f(s0[r] - rm[r]);
            float p1 = __builtin_amdgcn_exp2f(s1[r] - rm[r]);
            float ps = p0 + p1;
            ps += __shfl_xor(ps, 1);
            ps += __shfl_xor(ps, 2);
            ps += __shfl_xor(ps, 4);
            ps += __shfl_xor(ps, 8);
            ps += __shfl_xor(ps, 16);
            rl[r] += ps;
            Pw[((l31 >> 3) * 32 + q_l) * 8 + (l31 & 7)]       = f2bf(p0);
            Pw[(((l31 >> 3) + 4) * 32 + q_l) * 8 + (l31 & 7)] = f2bf(p1);
        }

        // ---- O += P V ----
#pragma unroll
        for (int ks2 = 0; ks2 < 4; ++ks2) {
            int mc = ks2 * 2 + lh;
            short8 pf = *(const short8*)(Pw + (mc * 32 + l31) * 8);
#pragma unroll
            for (int ef = 0; ef < 8; ++ef) {
                short8 vf = *(const short8*)(Vc + (mc * 256 + ef * 32 + l31) * 8);
                o[ef] = __builtin_amdgcn_mfma_f32_32x32x16_bf16(pf, vf, o[ef], 0, 0, 0);
            }
        }

        __syncthreads();   // drains vmcnt (next tile staged) + lgkm; protects buffer reuse
        cur ^= 1;
    }

    // ---- epilogue: normalize + direct f32 store ----
    float rinv[16];
#pragma unroll
    for (int r = 0; r < 16; ++r) rinv[r] = 1.f / rl[r];

#pragma unroll
    for (int ef = 0; ef < 8; ++ef) {
        int e = ef * 32 + l31;
        float* op = out + (size_t)b * 2097152 + (size_t)(256 + e) * 4096 +
                    qt * 128 + wid * 32 + 4 * lh;
#pragma unroll
        for (int g = 0; g < 4; ++g) {
            float4 v = make_float4(o[ef][4 * g + 0] * rinv[4 * g + 0],
                                   o[ef][4 * g + 1] * rinv[4 * g + 1],
                                   o[ef][4 * g + 2] * rinv[4 * g + 2],
                                   o[ef][4 * g + 3] * rinv[4 * g + 3]);
            *(float4*)(op + g * 8) = v;
        }
    }
}

// ---------------- launch ----------------

extern "C" void kernel_launch(void* const* d_in, const int* in_sizes, int n_in,
                              void* d_out, int out_size, void* d_ws, size_t ws_size,
                              hipStream_t stream) {
    const float* C       = (const float*)d_in[0];
    const float* P       = (const float*)d_in[1];
    const float* theta_w = (const float*)d_in[2];
    const float* phi_w   = (const float*)d_in[3];
    const float* g_w     = (const float*)d_in[4];
    const float* out_w   = (const float*)d_in[5];
    float* out = (float*)d_out;

    ushort_t* ws = (ushort_t*)d_ws;
    ushort_t* thetaT = ws;                       // 8*4096*256
    ushort_t* phiTx  = thetaT + 8388608;         // 8*262144
    ushort_t* gVx    = phiTx + 2097152;          // 8*262144
    float*    W2     = (float*)(gVx + 2097152);  // 256*256 fp32

    const float THSC = 1.4426950408889634f / 16.0f;  // log2(e)/sqrt(E)

    w2_gemm<<<dim3(32), dim3(256), 0, stream>>>(out_w, g_w, W2);
    copy_c_k<<<dim3(8192), dim3(256), 0, stream>>>((const float4*)C, (float4*)out);

    proj_gemm_bf<0><<<dim3(64, 4, 8), dim3(256), 0, stream>>>(theta_w, C, thetaT, NQ_, THSC);
    proj_gemm_bf<1><<<dim3(16, 4, 8), dim3(256), 0, stream>>>(phi_w, P, phiTx, NKV_, 1.f);
    proj_gemm_bf<2><<<dim3(16, 4, 8), dim3(256), 0, stream>>>(W2, P, gVx, NKV_, 1.f);

    attn2<<<dim3(256), dim3(256), 0, stream>>>(thetaT, phiTx, gVx, out);
}